// Round 1
// baseline (779.201 us; speedup 1.0000x reference)
//
#include <hip/hip_runtime.h>

// Segment softmax; min-stabilizer + eps cancel mathematically (see R2 notes):
// out = exp(d) / segment_sum(exp(d)).  |error| <= 2e-5 << 1.66e-2 threshold.
//
// Pipeline:
//   khist    : bucket histogram (bucket = seg>>7, 782 buckets)
//   kscan    : exclusive scan (1 block)
//   kscatter : counting-sort; perm[pos] = (edge<<7) | (seg&127)
//   kbsum    : grid (NB, S): bucket-slice blocks, LDS accum (stride-17 pad),
//              atomic-free partial writes under_part[S]
//              R3: 2 whole edges per thread per iter -> 8 float4 gathers in
//              flight (was 1 x 16B per quad, VGPR=8, latency-bound @825GB/s)
//   kreduce  : under = 1 / sum_s under_part[s]   (reciprocal hoisted here)
//   kout     : grid (NB, S): stage 1/under[bucket] in LDS, gather rows via
//              perm, out = exp * rcp, scatter 64B rows; same 2-edge MLP shape

#define NSEG 100000
#define D    16
#define WB   128      // segments per bucket
#define NB   782      // ceil(NSEG/WB)
#define S    4        // edge-slices per bucket
#define EPB  4096     // edges per block (hist/scatter)
#define TPB  256
#define PAD  17       // LDS stride per segment (16 data + 1 pad) -> all 32 banks

__global__ void khist(const int* __restrict__ idx, int n,
                      unsigned* __restrict__ counts) {
    __shared__ unsigned h[NB];
    for (int j = threadIdx.x; j < NB; j += TPB) h[j] = 0u;
    __syncthreads();
    int base = blockIdx.x * EPB;
#pragma unroll
    for (int it = 0; it < EPB / TPB; ++it) {
        int i = base + it * TPB + threadIdx.x;
        if (i < n) atomicAdd(&h[idx[i] >> 7], 1u);
    }
    __syncthreads();
    for (int j = threadIdx.x; j < NB; j += TPB) {
        unsigned c = h[j];
        if (c) atomicAdd(&counts[j], c);
    }
}

__global__ void kscan(const unsigned* __restrict__ counts,
                      unsigned* __restrict__ starts,
                      unsigned* __restrict__ offs) {
    __shared__ unsigned s[1024];
    int t = threadIdx.x;
    unsigned v = (t < NB) ? counts[t] : 0u;
    s[t] = v;
    __syncthreads();
    for (int d = 1; d < 1024; d <<= 1) {
        unsigned add = (t >= d) ? s[t - d] : 0u;
        __syncthreads();
        s[t] += add;
        __syncthreads();
    }
    if (t < NB) {
        unsigned ex = s[t] - v;
        starts[t] = ex;
        offs[t]   = ex;
    }
}

__global__ void kscatter(const int* __restrict__ idx, int n,
                         unsigned* __restrict__ offs,
                         unsigned* __restrict__ perm) {
    __shared__ unsigned h[NB];
    for (int j = threadIdx.x; j < NB; j += TPB) h[j] = 0u;
    __syncthreads();
    int base = blockIdx.x * EPB;
    int sg[EPB / TPB];
#pragma unroll
    for (int it = 0; it < EPB / TPB; ++it) {
        int i = base + it * TPB + threadIdx.x;
        sg[it] = (i < n) ? idx[i] : -1;
        if (sg[it] >= 0) atomicAdd(&h[sg[it] >> 7], 1u);
    }
    __syncthreads();
    for (int j = threadIdx.x; j < NB; j += TPB) {
        unsigned c = h[j];
        if (c) h[j] = atomicAdd(&offs[j], c);  // claim contiguous run
    }
    __syncthreads();
#pragma unroll
    for (int it = 0; it < EPB / TPB; ++it) {
        int i = base + it * TPB + threadIdx.x;
        if (sg[it] >= 0) {
            unsigned pos = atomicAdd(&h[sg[it] >> 7], 1u);
            perm[pos] = ((unsigned)i << 7) | ((unsigned)sg[it] & 127u);
        }
    }
}

__global__ __launch_bounds__(TPB, 4)
void kbsum(const float4* __restrict__ data,
           const unsigned* __restrict__ perm,
           const unsigned* __restrict__ starts,
           int n, float* __restrict__ under_part) {
    __shared__ float acc[WB * PAD];
    for (int j = threadIdx.x; j < WB * PAD; j += TPB) acc[j] = 0.f;
    __syncthreads();
    int bb = blockIdx.x, sl = blockIdx.y;
    unsigned b0 = starts[bb];
    unsigned b1 = (bb + 1 < NB) ? starts[bb + 1] : (unsigned)n;
    unsigned len = b1 - b0;
    unsigned s0 = b0 + (unsigned)(((unsigned long long)len * sl) / S);
    unsigned s1 = b0 + (unsigned)(((unsigned long long)len * (sl + 1)) / S);
    // 2 whole edges per thread per iteration: 2 perm loads then 8 independent
    // float4 gathers in flight before any use (MLP=8/thread, ~50 VGPR).
    for (unsigned p = s0 + 2u * threadIdx.x; p < s1; p += 2u * TPB) {
        bool has1   = (p + 1u < s1);
        unsigned pc = has1 ? p + 1u : p;   // clamped: no OOB speculative load
        unsigned u0 = perm[p];
        unsigned u1 = perm[pc];
        const float4* q0 = data + (size_t)(u0 >> 7) * 4;
        const float4* q1 = data + (size_t)(u1 >> 7) * 4;
        float4 a0 = q0[0], a1 = q0[1], a2 = q0[2], a3 = q0[3];
        float4 c0 = q1[0], c1 = q1[1], c2 = q1[2], c3 = q1[3];
        float* A = &acc[(u0 & 127u) * PAD];
        atomicAdd(A + 0,  __expf(a0.x)); atomicAdd(A + 1,  __expf(a0.y));
        atomicAdd(A + 2,  __expf(a0.z)); atomicAdd(A + 3,  __expf(a0.w));
        atomicAdd(A + 4,  __expf(a1.x)); atomicAdd(A + 5,  __expf(a1.y));
        atomicAdd(A + 6,  __expf(a1.z)); atomicAdd(A + 7,  __expf(a1.w));
        atomicAdd(A + 8,  __expf(a2.x)); atomicAdd(A + 9,  __expf(a2.y));
        atomicAdd(A + 10, __expf(a2.z)); atomicAdd(A + 11, __expf(a2.w));
        atomicAdd(A + 12, __expf(a3.x)); atomicAdd(A + 13, __expf(a3.y));
        atomicAdd(A + 14, __expf(a3.z)); atomicAdd(A + 15, __expf(a3.w));
        if (has1) {
            float* B = &acc[(u1 & 127u) * PAD];
            atomicAdd(B + 0,  __expf(c0.x)); atomicAdd(B + 1,  __expf(c0.y));
            atomicAdd(B + 2,  __expf(c0.z)); atomicAdd(B + 3,  __expf(c0.w));
            atomicAdd(B + 4,  __expf(c1.x)); atomicAdd(B + 5,  __expf(c1.y));
            atomicAdd(B + 6,  __expf(c1.z)); atomicAdd(B + 7,  __expf(c1.w));
            atomicAdd(B + 8,  __expf(c2.x)); atomicAdd(B + 9,  __expf(c2.y));
            atomicAdd(B + 10, __expf(c2.z)); atomicAdd(B + 11, __expf(c2.w));
            atomicAdd(B + 12, __expf(c3.x)); atomicAdd(B + 13, __expf(c3.y));
            atomicAdd(B + 14, __expf(c3.z)); atomicAdd(B + 15, __expf(c3.w));
        }
    }
    __syncthreads();
    float* outp = under_part + ((size_t)sl * NB + bb) * (WB * D);
    for (int j = threadIdx.x; j < WB * D; j += TPB)
        outp[j] = acc[(j >> 4) * PAD + (j & 15)];
}

__global__ void kreduce(const float4* __restrict__ part,
                        float4* __restrict__ under, int n4) {
    int i = blockIdx.x * blockDim.x + threadIdx.x;
    if (i >= n4) return;
    float4 a = part[i];
#pragma unroll
    for (int s = 1; s < S; ++s) {
        float4 b = part[(size_t)s * n4 + i];
        a.x += b.x; a.y += b.y; a.z += b.z; a.w += b.w;
    }
    // Store reciprocal: one full-precision divide per segment-element here
    // instead of one per edge-element in kout (1.6M vs 51.2M divides).
    a.x = 1.f / a.x; a.y = 1.f / a.y; a.z = 1.f / a.z; a.w = 1.f / a.w;
    under[i] = a;
}

__global__ __launch_bounds__(TPB, 4)
void kout(const float4* __restrict__ data,
          const unsigned* __restrict__ perm,
          const unsigned* __restrict__ starts,
          const float* __restrict__ under,
          int n, float4* __restrict__ out) {
    __shared__ float u_lds[WB * PAD];   // holds 1/under
    int bb = blockIdx.x, sl = blockIdx.y;
    const float* ub = under + (size_t)bb * (WB * D);
    for (int j = threadIdx.x; j < WB * D; j += TPB)
        u_lds[(j >> 4) * PAD + (j & 15)] = ub[j];
    __syncthreads();
    unsigned b0 = starts[bb];
    unsigned b1 = (bb + 1 < NB) ? starts[bb + 1] : (unsigned)n;
    unsigned len = b1 - b0;
    unsigned s0 = b0 + (unsigned)(((unsigned long long)len * sl) / S);
    unsigned s1 = b0 + (unsigned)(((unsigned long long)len * (sl + 1)) / S);
    for (unsigned p = s0 + 2u * threadIdx.x; p < s1; p += 2u * TPB) {
        bool has1   = (p + 1u < s1);
        unsigned pc = has1 ? p + 1u : p;
        unsigned u0 = perm[p];
        unsigned u1 = perm[pc];
        size_t e0 = (size_t)(u0 >> 7) * 4;
        size_t e1 = (size_t)(u1 >> 7) * 4;
        float4 a0 = data[e0 + 0], a1 = data[e0 + 1],
               a2 = data[e0 + 2], a3 = data[e0 + 3];
        float4 c0 = data[e1 + 0], c1 = data[e1 + 1],
               c2 = data[e1 + 2], c3 = data[e1 + 3];
        const float* U = &u_lds[(u0 & 127u) * PAD];
        float4 o0, o1, o2, o3;
        o0.x = __expf(a0.x) * U[0];  o0.y = __expf(a0.y) * U[1];
        o0.z = __expf(a0.z) * U[2];  o0.w = __expf(a0.w) * U[3];
        o1.x = __expf(a1.x) * U[4];  o1.y = __expf(a1.y) * U[5];
        o1.z = __expf(a1.z) * U[6];  o1.w = __expf(a1.w) * U[7];
        o2.x = __expf(a2.x) * U[8];  o2.y = __expf(a2.y) * U[9];
        o2.z = __expf(a2.z) * U[10]; o2.w = __expf(a2.w) * U[11];
        o3.x = __expf(a3.x) * U[12]; o3.y = __expf(a3.y) * U[13];
        o3.z = __expf(a3.z) * U[14]; o3.w = __expf(a3.w) * U[15];
        out[e0 + 0] = o0; out[e0 + 1] = o1;
        out[e0 + 2] = o2; out[e0 + 3] = o3;
        if (has1) {
            const float* V = &u_lds[(u1 & 127u) * PAD];
            float4 r0, r1, r2, r3;
            r0.x = __expf(c0.x) * V[0];  r0.y = __expf(c0.y) * V[1];
            r0.z = __expf(c0.z) * V[2];  r0.w = __expf(c0.w) * V[3];
            r1.x = __expf(c1.x) * V[4];  r1.y = __expf(c1.y) * V[5];
            r1.z = __expf(c1.z) * V[6];  r1.w = __expf(c1.w) * V[7];
            r2.x = __expf(c2.x) * V[8];  r2.y = __expf(c2.y) * V[9];
            r2.z = __expf(c2.z) * V[10]; r2.w = __expf(c2.w) * V[11];
            r3.x = __expf(c3.x) * V[12]; r3.y = __expf(c3.y) * V[13];
            r3.z = __expf(c3.z) * V[14]; r3.w = __expf(c3.w) * V[15];
            out[e1 + 0] = r0; out[e1 + 1] = r1;
            out[e1 + 2] = r2; out[e1 + 3] = r3;
        }
    }
}

extern "C" void kernel_launch(void* const* d_in, const int* in_sizes, int n_in,
                              void* d_out, int out_size, void* d_ws, size_t ws_size,
                              hipStream_t stream) {
    const float4* data = (const float4*)d_in[0];
    const int*    idx  = (const int*)d_in[1];
    int n = in_sizes[0] / D;           // 3.2M edges

    // ws layout: under (6.4MB) | under_part (25.6MB) | perm (12.8MB) | counts/starts/offs
    char* ws = (char*)d_ws;
    size_t seg_f = (size_t)NB * WB * D;               // 1,601,536 floats
    float*    under  = (float*)ws;
    float*    upart  = under + seg_f;
    unsigned* perm   = (unsigned*)(upart + seg_f * S);
    unsigned* counts = perm + (size_t)n;
    unsigned* starts = counts + NB;
    unsigned* offs   = starts + NB;

    hipMemsetAsync(counts, 0, NB * sizeof(unsigned), stream);

    int hblocks = (n + EPB - 1) / EPB;
    khist   <<<hblocks, TPB, 0, stream>>>(idx, n, counts);
    kscan   <<<1, 1024, 0, stream>>>(counts, starts, offs);
    kscatter<<<hblocks, TPB, 0, stream>>>(idx, n, offs, perm);
    kbsum   <<<dim3(NB, S), TPB, 0, stream>>>(data, perm, starts, n, upart);
    int n4 = (int)(seg_f / 4);
    kreduce <<<(n4 + TPB - 1) / TPB, TPB, 0, stream>>>((const float4*)upart,
                                                       (float4*)under, n4);
    kout    <<<dim3(NB, S), TPB, 0, stream>>>(data, perm, starts, under, n,
                                              (float4*)d_out);
}